// Round 1
// baseline (1201.224 us; speedup 1.0000x reference)
//
#include <hip/hip_runtime.h>

// ---------------- common helpers ----------------
typedef unsigned short ushortT;
typedef unsigned int uint32;
typedef __attribute__((ext_vector_type(8))) short short8;
typedef __attribute__((ext_vector_type(4))) float f32x4;

__device__ __forceinline__ ushortT f2bf(float f) {
    uint32 u = __float_as_uint(f);
    uint32 r = (u + 0x7fffu + ((u >> 16) & 1u)) >> 16;
    return (ushortT)r;
}
__device__ __forceinline__ float bf2f(ushortT v) {
    return __uint_as_float(((uint32)v) << 16);
}

// ---------------- fp32 -> bf16 convert (vectorized) ----------------
__global__ __launch_bounds__(256) void f32_to_bf16_kernel(
    const float* __restrict__ src, ushortT* __restrict__ dst, int n4)
{
    int i = blockIdx.x * 256 + threadIdx.x;
    if (i < n4) {
        float4 v = reinterpret_cast<const float4*>(src)[i];
        ushort4 o;
        o.x = f2bf(v.x); o.y = f2bf(v.y); o.z = f2bf(v.z); o.w = f2bf(v.w);
        reinterpret_cast<ushort4*>(dst)[i] = o;
    }
}

// ---------------- RoPE cos/sin table: [T][16] float2 ----------------
__global__ __launch_bounds__(256) void rope_table_kernel(float2* __restrict__ tab)
{
    int idx = blockIdx.x * 256 + threadIdx.x;   // T*16 = 131072 entries
    int t = idx >> 4;
    int i = idx & 15;
    float inv = powf(10000.0f, -(float)i / 16.0f);
    float ang = (float)t * inv;
    tab[idx] = make_float2(cosf(ang), sinf(ang));
}

// ---------------- bf16 MFMA GEMM: C = A(MxK) * W(NxK)^T + bias ----------------
// OUTMODE 0: bf16 out only (q)
// OUTMODE 1: bf16 out + fp32 "present" out in (B,H,T,64) layout (k, v)
// OUTMODE 2: fp32 out only (final projection)
template<int OUTMODE>
__global__ __launch_bounds__(256) void gemm_kernel(
    const ushortT* __restrict__ A,   // M x K bf16
    const ushortT* __restrict__ W,   // N x K bf16 (row-major = B^T)
    const float*   __restrict__ bias,// N fp32
    ushortT*       __restrict__ Cb,  // M x N bf16 (modes 0,1)
    float*         __restrict__ Cf,  // mode1: present base; mode2: M x N fp32
    int M, int N, int K)
{
    __shared__ ushortT As[128 * 32];
    __shared__ ushortT Bs[128 * 32];
    const int tid  = threadIdx.x;
    const int lane = tid & 63;
    const int wv   = tid >> 6;
    const int wm   = wv >> 1;   // wave row (0..1)
    const int wn   = wv & 1;    // wave col (0..1)
    const int m0   = blockIdx.y * 128;
    const int n0   = blockIdx.x * 128;

    f32x4 acc[4][4] = {};

    // staging chunks: tile = 128 rows x 32 cols bf16 = 8192B = 512 x 16B chunks
    // chunk c: row = c>>2, col = (c&3)*8 ; thread handles c = tid and tid+256
    const int r0  = tid >> 2,          cc0 = (tid & 3) * 8;
    const int r1  = (tid + 256) >> 2,  cc1 = ((tid + 256) & 3) * 8;

    const ushortT* Ar0 = A + (size_t)(m0 + r0) * K + cc0;
    const ushortT* Ar1 = A + (size_t)(m0 + r1) * K + cc1;
    const ushortT* Wr0 = W + (size_t)(n0 + r0) * K + cc0;
    const ushortT* Wr1 = W + (size_t)(n0 + r1) * K + cc1;

    const int kq   = (lane >> 4) * 8;   // k sub-block for this lane
    const int rsel = lane & 15;         // row/col within 16

    for (int k0 = 0; k0 < K; k0 += 32) {
        uint4 a0 = *reinterpret_cast<const uint4*>(Ar0 + k0);
        uint4 a1 = *reinterpret_cast<const uint4*>(Ar1 + k0);
        uint4 b0 = *reinterpret_cast<const uint4*>(Wr0 + k0);
        uint4 b1 = *reinterpret_cast<const uint4*>(Wr1 + k0);
        __syncthreads();
        *reinterpret_cast<uint4*>(As + r0 * 32 + cc0) = a0;
        *reinterpret_cast<uint4*>(As + r1 * 32 + cc1) = a1;
        *reinterpret_cast<uint4*>(Bs + r0 * 32 + cc0) = b0;
        *reinterpret_cast<uint4*>(Bs + r1 * 32 + cc1) = b1;
        __syncthreads();

        short8 af[4], bfr[4];
        #pragma unroll
        for (int i = 0; i < 4; ++i) {
            af[i]  = *reinterpret_cast<const short8*>(As + (wm * 64 + i * 16 + rsel) * 32 + kq);
            bfr[i] = *reinterpret_cast<const short8*>(Bs + (wn * 64 + i * 16 + rsel) * 32 + kq);
        }
        #pragma unroll
        for (int i = 0; i < 4; ++i)
            #pragma unroll
            for (int j = 0; j < 4; ++j)
                acc[i][j] = __builtin_amdgcn_mfma_f32_16x16x32_bf16(af[i], bfr[j], acc[i][j], 0, 0, 0);
    }

    // epilogue: C/D layout col = lane&15, row = (lane>>4)*4 + e
    #pragma unroll
    for (int j = 0; j < 4; ++j) {
        const int colb = n0 + wn * 64 + j * 16 + rsel;
        const float bv = bias[colb];
        #pragma unroll
        for (int i = 0; i < 4; ++i) {
            #pragma unroll
            for (int e = 0; e < 4; ++e) {
                const int row = m0 + wm * 64 + i * 16 + (lane >> 4) * 4 + e;
                const float val = acc[i][j][e] + bv;
                if (OUTMODE != 2) Cb[(size_t)row * N + colb] = f2bf(val);
                if (OUTMODE == 1) {
                    // present: (B, H, T, 64) fp32, T = 8192
                    const int b = row >> 13, t = row & 8191;
                    const int h = colb >> 6, d = colb & 63;
                    Cf[(((size_t)b * 16 + h) * 8192 + t) * 64 + d] = val;
                }
                if (OUTMODE == 2) Cf[(size_t)row * N + colb] = val;
            }
        }
    }
}

// ---------------- RoPE helper: lane = dim (0..63), rot_dim = 32 ----------------
__device__ __forceinline__ float rope_val(float x, int lane, int t, const float2* __restrict__ tab)
{
    float pair = __shfl_xor(x, 1, 64);   // uniform: all lanes participate
    if (lane < 32) {
        float2 cs = tab[t * 16 + (lane >> 1)];
        float rot = (lane & 1) ? pair : -pair;
        return fmaf(x, cs.x, rot * cs.y);
    }
    return x;
}

// ---------------- neighborhood attention: one wave per (b,h,t) ----------------
__global__ __launch_bounds__(256) void natt_kernel(
    const ushortT* __restrict__ Q,
    const ushortT* __restrict__ Kl,
    const ushortT* __restrict__ Vl,
    const float2*  __restrict__ tab,
    ushortT*       __restrict__ O)
{
    const int T = 8192;
    const int wid  = blockIdx.x * 4 + (threadIdx.x >> 6);
    const int lane = threadIdx.x & 63;
    const int t = wid & (T - 1);
    const int h = (wid >> 13) & 15;
    const int b = wid >> 17;

    const int dils[4] = {1, 4, 8, 16};
    const int dd = dils[h >> 2];

    const int r = t % dd, p = t / dd;
    int s = p - 3;
    const int smax = T / dd - 7;
    s = s < 0 ? 0 : (s > smax ? smax : s);
    const int tbase = r + s * dd;          // neighbor j at tbase + j*dd

    const size_t qoff = ((size_t)(b * T + t)) * 1024 + h * 64 + lane;
    const float qr = rope_val(bf2f(Q[qoff]), lane, t, tab);

    const size_t koff = ((size_t)b * T + tbase) * 1024 + h * 64 + lane;

    float sc[7];
    #pragma unroll
    for (int j = 0; j < 7; ++j) {
        const int tj = tbase + j * dd;
        const float kr = rope_val(bf2f(Kl[koff + (size_t)(j * dd) * 1024]), lane, tj, tab);
        float pp = qr * kr;
        #pragma unroll
        for (int off = 32; off > 0; off >>= 1) pp += __shfl_xor(pp, off, 64);
        sc[j] = pp;
    }

    float mx = sc[0];
    #pragma unroll
    for (int j = 1; j < 7; ++j) mx = fmaxf(mx, sc[j]);
    float den = 0.f;
    #pragma unroll
    for (int j = 0; j < 7; ++j) { sc[j] = __expf(sc[j] - mx); den += sc[j]; }

    float accv = 0.f;
    #pragma unroll
    for (int j = 0; j < 7; ++j) {
        const int tj = tbase + j * dd;
        const float vr = rope_val(bf2f(Vl[koff + (size_t)(j * dd) * 1024]), lane, tj, tab);
        accv = fmaf(sc[j], vr, accv);
    }
    O[qoff] = f2bf(accv / den);
}

// ---------------- launcher ----------------
extern "C" void kernel_launch(void* const* d_in, const int* in_sizes, int n_in,
                              void* d_out, int out_size, void* d_ws, size_t ws_size,
                              hipStream_t stream)
{
    const float* x  = (const float*)d_in[0];
    const float* wq = (const float*)d_in[1];
    const float* bq = (const float*)d_in[2];
    const float* wk = (const float*)d_in[3];
    const float* bk = (const float*)d_in[4];
    const float* wv = (const float*)d_in[5];
    const float* bv = (const float*)d_in[6];
    const float* wp = (const float*)d_in[7];
    const float* bp = (const float*)d_in[8];

    const int B = 4, T = 8192, C = 1024;
    const int M = B * T;                    // 32768
    const size_t MC = (size_t)M * C;        // 33,554,432

    char* ws = (char*)d_ws;
    ushortT* xb   = (ushortT*)ws;                                   // 64MB (reused as attn out)
    ushortT* wqb  = (ushortT*)(ws + (size_t)64 * 1024 * 1024);
    ushortT* wkb  = wqb + (size_t)C * C;
    ushortT* wvb  = wkb + (size_t)C * C;
    ushortT* wpb  = wvb + (size_t)C * C;
    ushortT* qlin = (ushortT*)(ws + (size_t)72 * 1024 * 1024);      // 64MB
    ushortT* klin = qlin + MC;                                      // 64MB
    ushortT* vlin = klin + MC;                                      // 64MB
    float2*  tab  = (float2*)(ws + (size_t)264 * 1024 * 1024);      // 1MB

    float* y     = (float*)d_out;
    float* presK = y + MC;
    float* presV = presK + MC;

    rope_table_kernel<<<512, 256, 0, stream>>>(tab);

    f32_to_bf16_kernel<<<(int)(MC / 4 / 256), 256, 0, stream>>>(x, xb, (int)(MC / 4));
    const int wn4 = C * C / 4;
    f32_to_bf16_kernel<<<(wn4 + 255) / 256, 256, 0, stream>>>(wq, wqb, wn4);
    f32_to_bf16_kernel<<<(wn4 + 255) / 256, 256, 0, stream>>>(wk, wkb, wn4);
    f32_to_bf16_kernel<<<(wn4 + 255) / 256, 256, 0, stream>>>(wv, wvb, wn4);
    f32_to_bf16_kernel<<<(wn4 + 255) / 256, 256, 0, stream>>>(wp, wpb, wn4);

    dim3 gg(C / 128, M / 128);   // (8, 256): x = n-tile, y = m-tile
    gemm_kernel<0><<<gg, 256, 0, stream>>>(xb, wqb, bq, qlin, nullptr, M, C, C);
    gemm_kernel<1><<<gg, 256, 0, stream>>>(xb, wkb, bk, klin, presK, M, C, C);
    gemm_kernel<1><<<gg, 256, 0, stream>>>(xb, wvb, bv, vlin, presV, M, C, C);

    natt_kernel<<<(B * 16 * T) / 4, 256, 0, stream>>>(qlin, klin, vlin, tab, xb);

    gemm_kernel<2><<<gg, 256, 0, stream>>>(xb, wpb, bp, nullptr, y, M, C, C);
}

// Round 2
// 673.651 us; speedup vs baseline: 1.7832x; 1.7832x over previous
//
#include <hip/hip_runtime.h>

// ---------------- common helpers ----------------
typedef unsigned short ushortT;
typedef unsigned int uint32;
typedef __attribute__((ext_vector_type(8))) short short8;
typedef __attribute__((ext_vector_type(4))) float f32x4;

__device__ __forceinline__ ushortT f2bf(float f) {
    uint32 u = __float_as_uint(f);
    uint32 r = (u + 0x7fffu + ((u >> 16) & 1u)) >> 16;
    return (ushortT)r;
}
__device__ __forceinline__ float bf2f(uint32 v) {
    return __uint_as_float(v << 16);
}

__device__ __forceinline__ void unpack8(uint4 v, float* f) {
    f[0] = bf2f(v.x & 0xffffu); f[1] = bf2f(v.x >> 16);
    f[2] = bf2f(v.y & 0xffffu); f[3] = bf2f(v.y >> 16);
    f[4] = bf2f(v.z & 0xffffu); f[5] = bf2f(v.z >> 16);
    f[6] = bf2f(v.w & 0xffffu); f[7] = bf2f(v.w >> 16);
}

// async global->LDS, 16B per lane. LDS dest must be wave-uniform base;
// HW writes lane i at base + i*16.
typedef __attribute__((address_space(1))) const void gvoid;
typedef __attribute__((address_space(3))) void lvoid;
__device__ __forceinline__ void gld16(const ushortT* g, ushortT* l) {
    __builtin_amdgcn_global_load_lds((gvoid*)g, (lvoid*)l, 16, 0, 0);
}

// ---------------- fp32 -> bf16 convert (vectorized) ----------------
__global__ __launch_bounds__(256) void f32_to_bf16_kernel(
    const float* __restrict__ src, ushortT* __restrict__ dst, int n4)
{
    int i = blockIdx.x * 256 + threadIdx.x;
    if (i < n4) {
        float4 v = reinterpret_cast<const float4*>(src)[i];
        ushort4 o;
        o.x = f2bf(v.x); o.y = f2bf(v.y); o.z = f2bf(v.z); o.w = f2bf(v.w);
        reinterpret_cast<ushort4*>(dst)[i] = o;
    }
}

// ---------------- RoPE cos/sin table: [T][16] float2 ----------------
__global__ __launch_bounds__(256) void rope_table_kernel(float2* __restrict__ tab)
{
    int idx = blockIdx.x * 256 + threadIdx.x;   // T*16 = 131072 entries
    int t = idx >> 4;
    int i = idx & 15;
    float inv = powf(10000.0f, -(float)i / 16.0f);
    float ang = (float)t * inv;
    tab[idx] = make_float2(cosf(ang), sinf(ang));
}

// ---------------- bf16 MFMA GEMM: C = A(MxK) * W(NxK)^T + bias ----------------
// MODE 0: rope -> bf16 out (q)
// MODE 1: fp32 "present" out (pre-rope, (B,H,T,64)) + rope -> bf16 out (k, v)
// MODE 2: fp32 out, no rope (final projection)
template<int MODE>
__global__ __launch_bounds__(256) void gemm_kernel(
    const ushortT* __restrict__ A,   // M x K bf16
    const ushortT* __restrict__ W,   // N x K bf16 (row-major = B^T)
    const float*   __restrict__ bias,// N fp32
    const float2*  __restrict__ tab, // rope table [T][16]
    ushortT*       __restrict__ Cb,  // M x N bf16 (modes 0,1)
    float*         __restrict__ Cf,  // mode1: present base; mode2: M x N fp32
    int M, int N, int K)
{
    __shared__ ushortT As[128 * 32];
    __shared__ ushortT Bs[128 * 32];
    const int tid  = threadIdx.x;
    const int lane = tid & 63;
    const int wv   = tid >> 6;
    const int wm   = wv >> 1;   // wave row (0..1)
    const int wn   = wv & 1;    // wave col (0..1)
    const int m0   = blockIdx.y * 128;
    const int n0   = blockIdx.x * 128;

    f32x4 acc[4][4] = {};

    // staging: tile = 128 rows x 32 cols bf16 = 512 chunks of 16B
    // chunk c -> row = c>>2, col = (c&3)*8 ; LDS offset = c*16B (linear)
    const int r0  = tid >> 2,          cc0 = (tid & 3) * 8;
    const int r1  = (tid + 256) >> 2,  cc1 = ((tid + 256) & 3) * 8;

    const ushortT* Ag0 = A + (size_t)(m0 + r0) * K + cc0;
    const ushortT* Ag1 = A + (size_t)(m0 + r1) * K + cc1;
    const ushortT* Wg0 = W + (size_t)(n0 + r0) * K + cc0;
    const ushortT* Wg1 = W + (size_t)(n0 + r1) * K + cc1;

    // wave-uniform LDS bases (ushort units): set0 chunks tid, set1 chunks tid+256
    ushortT* As0 = As + wv * 512;
    ushortT* As1 = As + 2048 + wv * 512;
    ushortT* Bs0 = Bs + wv * 512;
    ushortT* Bs1 = Bs + 2048 + wv * 512;

    const int kq   = (lane >> 4) * 8;   // k sub-block for this lane
    const int rsel = lane & 15;         // row/col within 16

    for (int k0 = 0; k0 < K; k0 += 32) {
        gld16(Ag0 + k0, As0);
        gld16(Ag1 + k0, As1);
        gld16(Wg0 + k0, Bs0);
        gld16(Wg1 + k0, Bs1);
        __syncthreads();   // drains vmcnt -> LDS valid

        short8 af[4], bfr[4];
        #pragma unroll
        for (int i = 0; i < 4; ++i) {
            af[i]  = *reinterpret_cast<const short8*>(As + (wm * 64 + i * 16 + rsel) * 32 + kq);
            bfr[i] = *reinterpret_cast<const short8*>(Bs + (wn * 64 + i * 16 + rsel) * 32 + kq);
        }
        #pragma unroll
        for (int i = 0; i < 4; ++i)
            #pragma unroll
            for (int j = 0; j < 4; ++j)
                acc[i][j] = __builtin_amdgcn_mfma_f32_16x16x32_bf16(af[i], bfr[j], acc[i][j], 0, 0, 0);
        __syncthreads();   // protect LDS before next stage
    }

    // epilogue: C/D layout col = lane&15, row = (lane>>4)*4 + e
    #pragma unroll
    for (int j = 0; j < 4; ++j) {
        const int colb = n0 + wn * 64 + j * 16 + rsel;
        const int d    = colb & 63;          // dim within head
        const float bv = bias[colb];
        #pragma unroll
        for (int i = 0; i < 4; ++i) {
            const int rowbase = m0 + wm * 64 + i * 16 + (lane >> 4) * 4;
            #pragma unroll
            for (int e = 0; e < 4; ++e) {
                const int row = rowbase + e;
                const float val = acc[i][j][e] + bv;
                if (MODE == 1) {
                    // present: (B, H, T, 64) fp32, pre-rope
                    const int b = row >> 13, t = row & 8191;
                    const int h = colb >> 6;
                    Cf[(((size_t)b * 16 + h) * 8192 + t) * 64 + d] = val;
                }
                if (MODE == 2) {
                    Cf[(size_t)row * N + colb] = val;
                } else {
                    // rope: pair (d, d^1) sits at lane^1, same row
                    const float pv = __shfl_xor(val, 1, 64);
                    float ov = val;
                    if (d < 32) {
                        const int t = row & 8191;
                        const float2 cs = tab[t * 16 + (d >> 1)];
                        ov = (d & 1) ? fmaf(val, cs.x,  pv * cs.y)
                                     : fmaf(val, cs.x, -pv * cs.y);
                    }
                    Cb[(size_t)row * N + colb] = f2bf(ov);
                }
            }
        }
    }
}

// ---------------- neighborhood attention ----------------
// wave = 8 queries x 8 dim-chunks; lane = tloc*8 + c  (8 consecutive lanes
// cover one contiguous 128B row segment). q/k/v already roped.
__global__ __launch_bounds__(256) void natt_kernel(
    const ushortT* __restrict__ Q,
    const ushortT* __restrict__ Kl,
    const ushortT* __restrict__ Vl,
    ushortT*       __restrict__ O)
{
    const int T = 8192;
    const int tid  = threadIdx.x;
    const int lane = tid & 63;
    const int tloc = lane >> 3;
    const int c    = lane & 7;

    const int wq   = (blockIdx.x * 256 + tid) >> 6;  // wave-group id
    const int qidx = wq * 8 + tloc;
    const int t = qidx & (T - 1);
    const int h = (qidx >> 13) & 15;
    const int b = qidx >> 17;

    const int shifts[4] = {0, 2, 3, 4};
    const int sh = shifts[h >> 2];
    const int dd = 1 << sh;

    const int r  = t & (dd - 1);
    const int p  = t >> sh;
    const int Lr = ((T - 1 - r) >> sh) + 1;
    int s = p - 3;
    const int smax = Lr - 7;
    s = s < 0 ? 0 : (s > smax ? smax : s);
    const int tbase = r + (s << sh);

    const size_t qoff = ((size_t)(b * T + t)) * 1024 + h * 64 + c * 8;
    float qf[8];
    unpack8(*reinterpret_cast<const uint4*>(Q + qoff), qf);

    const size_t cbase = ((size_t)b * T) * 1024 + h * 64 + c * 8;

    float sc[7];
    #pragma unroll
    for (int j = 0; j < 7; ++j) {
        const int tj = tbase + (j << sh);
        float kf[8];
        unpack8(*reinterpret_cast<const uint4*>(Kl + cbase + (size_t)tj * 1024), kf);
        float pp = 0.f;
        #pragma unroll
        for (int i = 0; i < 8; ++i) pp = fmaf(qf[i], kf[i], pp);
        pp += __shfl_xor(pp, 1, 64);
        pp += __shfl_xor(pp, 2, 64);
        pp += __shfl_xor(pp, 4, 64);
        sc[j] = pp;
    }

    float mx = sc[0];
    #pragma unroll
    for (int j = 1; j < 7; ++j) mx = fmaxf(mx, sc[j]);
    float den = 0.f;
    #pragma unroll
    for (int j = 0; j < 7; ++j) { sc[j] = __expf(sc[j] - mx); den += sc[j]; }
    const float inv = 1.0f / den;

    float out[8] = {};
    #pragma unroll
    for (int j = 0; j < 7; ++j) {
        const int tj = tbase + (j << sh);
        float vf[8];
        unpack8(*reinterpret_cast<const uint4*>(Vl + cbase + (size_t)tj * 1024), vf);
        #pragma unroll
        for (int i = 0; i < 8; ++i) out[i] = fmaf(sc[j], vf[i], out[i]);
    }

    short8 ov;
    #pragma unroll
    for (int i = 0; i < 8; ++i) ov[i] = (short)f2bf(out[i] * inv);
    *reinterpret_cast<short8*>(const_cast<ushortT*>(O + qoff)) = ov;
}

// ---------------- launcher ----------------
extern "C" void kernel_launch(void* const* d_in, const int* in_sizes, int n_in,
                              void* d_out, int out_size, void* d_ws, size_t ws_size,
                              hipStream_t stream)
{
    const float* x  = (const float*)d_in[0];
    const float* wq = (const float*)d_in[1];
    const float* bq = (const float*)d_in[2];
    const float* wk = (const float*)d_in[3];
    const float* bk = (const float*)d_in[4];
    const float* wv = (const float*)d_in[5];
    const float* bv = (const float*)d_in[6];
    const float* wp = (const float*)d_in[7];
    const float* bp = (const float*)d_in[8];

    const int B = 4, T = 8192, C = 1024;
    const int M = B * T;                    // 32768
    const size_t MC = (size_t)M * C;        // 33,554,432

    char* ws = (char*)d_ws;
    ushortT* xb   = (ushortT*)ws;                                   // 64MB (reused as attn out)
    ushortT* wqb  = (ushortT*)(ws + (size_t)64 * 1024 * 1024);
    ushortT* wkb  = wqb + (size_t)C * C;
    ushortT* wvb  = wkb + (size_t)C * C;
    ushortT* wpb  = wvb + (size_t)C * C;
    ushortT* qlin = (ushortT*)(ws + (size_t)72 * 1024 * 1024);      // 64MB
    ushortT* klin = qlin + MC;                                      // 64MB
    ushortT* vlin = klin + MC;                                      // 64MB
    float2*  tab  = (float2*)(ws + (size_t)264 * 1024 * 1024);      // 1MB

    float* y     = (float*)d_out;
    float* presK = y + MC;
    float* presV = presK + MC;

    rope_table_kernel<<<512, 256, 0, stream>>>(tab);

    f32_to_bf16_kernel<<<(int)(MC / 4 / 256), 256, 0, stream>>>(x, xb, (int)(MC / 4));
    const int wn4 = C * C / 4;
    f32_to_bf16_kernel<<<(wn4 + 255) / 256, 256, 0, stream>>>(wq, wqb, wn4);
    f32_to_bf16_kernel<<<(wn4 + 255) / 256, 256, 0, stream>>>(wk, wkb, wn4);
    f32_to_bf16_kernel<<<(wn4 + 255) / 256, 256, 0, stream>>>(wv, wvb, wn4);
    f32_to_bf16_kernel<<<(wn4 + 255) / 256, 256, 0, stream>>>(wp, wpb, wn4);

    dim3 gg(C / 128, M / 128);   // (8, 256): x = n-tile, y = m-tile
    gemm_kernel<0><<<gg, 256, 0, stream>>>(xb, wqb, bq, tab, qlin, nullptr, M, C, C);
    gemm_kernel<1><<<gg, 256, 0, stream>>>(xb, wkb, bk, tab, klin, presK, M, C, C);
    gemm_kernel<1><<<gg, 256, 0, stream>>>(xb, wvb, bv, tab, vlin, presV, M, C, C);

    natt_kernel<<<(B * 16 * T) / 32, 256, 0, stream>>>(qlin, klin, vlin, xb);

    gemm_kernel<2><<<gg, 256, 0, stream>>>(xb, wpb, bp, tab, nullptr, y, M, C, C);
}

// Round 3
// 622.966 us; speedup vs baseline: 1.9282x; 1.0814x over previous
//
#include <hip/hip_runtime.h>

// ---------------- common helpers ----------------
typedef unsigned short ushortT;
typedef unsigned int uint32;
typedef __attribute__((ext_vector_type(8))) short short8;
typedef __attribute__((ext_vector_type(4))) float f32x4;

__device__ __forceinline__ ushortT f2bf(float f) {
    uint32 u = __float_as_uint(f);
    uint32 r = (u + 0x7fffu + ((u >> 16) & 1u)) >> 16;
    return (ushortT)r;
}
__device__ __forceinline__ float bf2f(uint32 v) {
    return __uint_as_float(v << 16);
}

__device__ __forceinline__ void unpack8(uint4 v, float* f) {
    f[0] = bf2f(v.x & 0xffffu); f[1] = bf2f(v.x >> 16);
    f[2] = bf2f(v.y & 0xffffu); f[3] = bf2f(v.y >> 16);
    f[4] = bf2f(v.z & 0xffffu); f[5] = bf2f(v.z >> 16);
    f[6] = bf2f(v.w & 0xffffu); f[7] = bf2f(v.w >> 16);
}

// async global->LDS, 16B per lane. LDS dest must be wave-uniform base;
// HW writes lane i at base + i*16.
typedef __attribute__((address_space(1))) const void gvoid;
typedef __attribute__((address_space(3))) void lvoid;
__device__ __forceinline__ void gld16(const ushortT* g, ushortT* l) {
    __builtin_amdgcn_global_load_lds((gvoid*)g, (lvoid*)l, 16, 0, 0);
}

// ---------------- fp32 -> bf16 convert (vectorized) ----------------
__global__ __launch_bounds__(256) void f32_to_bf16_kernel(
    const float* __restrict__ src, ushortT* __restrict__ dst, int n4)
{
    int i = blockIdx.x * 256 + threadIdx.x;
    if (i < n4) {
        float4 v = reinterpret_cast<const float4*>(src)[i];
        ushort4 o;
        o.x = f2bf(v.x); o.y = f2bf(v.y); o.z = f2bf(v.z); o.w = f2bf(v.w);
        reinterpret_cast<ushort4*>(dst)[i] = o;
    }
}

// ---------------- RoPE cos/sin table: [T][16] float2 ----------------
__global__ __launch_bounds__(256) void rope_table_kernel(float2* __restrict__ tab)
{
    int idx = blockIdx.x * 256 + threadIdx.x;   // T*16 = 131072 entries
    int t = idx >> 4;
    int i = idx & 15;
    float inv = powf(10000.0f, -(float)i / 16.0f);
    float ang = (float)t * inv;
    tab[idx] = make_float2(cosf(ang), sinf(ang));
}

// ---------------- 256x256 deep-pipelined bf16 MFMA GEMM ----------------
// C = A(MxK) * W(NxK)^T + bias.  BK=32, 4 LDS buffers, 8 waves (2m x 4n),
// per-wave out 128x64 (acc[8][4] 16x16 frags). 2 phases per K-tile:
//   phase A: ds_read B(4)+A(4) frags | stage A-half of tile t+3 | barrier |
//            lgkmcnt(0) | setprio(1) 16 MFMA setprio(0) | barrier
//   phase B: ds_read A(4) frags      | stage B-half of tile t+3 | vmcnt(8) |
//            barrier | lgkmcnt(0) | setprio(1) 16 MFMA setprio(0) | barrier
// Staging tile t+3 targets buf (t+3)&3 == buf (t-1)&3, idle since the last
// barrier of tile t-1 -> no write-to-live-buffer race, no latency assumption.
// vmcnt(8) leaves tiles t+2,t+3 (8 loads) in flight, guarantees t+1 landed.
// LDS swizzle (both sides): element e ^= ((row>>1)&3)<<3  (row = e>>5).
//
// MODE 0: rope -> bf16 out (q)
// MODE 1: fp32 "present" out (pre-rope, (B,H,T,64)) + rope -> bf16 out (k,v)
// MODE 2: fp32 out, no rope (final projection)

__device__ __forceinline__ short8 ldsfrag(const ushortT* region, int row, int g) {
    int e = (row << 5) + (g << 3);
    e ^= ((row >> 1) & 3) << 3;
    return *reinterpret_cast<const short8*>(region + e);
}

template<int MODE>
__global__ __launch_bounds__(512, 2) void gemm256_kernel(
    const ushortT* __restrict__ A,   // M x K bf16
    const ushortT* __restrict__ W,   // N x K bf16 (row-major = B^T)
    const float*   __restrict__ bias,
    const float2*  __restrict__ tab, // rope table [T][16]
    ushortT*       __restrict__ Cb,  // M x N bf16 (modes 0,1)
    float*         __restrict__ Cf,  // mode1: present base; mode2: M x N fp32
    int M, int N, int K)
{
    extern __shared__ ushortT lds[];   // 4 bufs x (A 8192 + B 8192) elems = 128 KB
    const int tid  = threadIdx.x;
    const int lane = tid & 63;
    const int wv   = tid >> 6;        // 0..7
    const int wm   = wv >> 2;         // 0..1  (wave row: 128 rows)
    const int wn   = wv & 3;          // 0..3  (wave col: 64 cols)
    const int g    = lane >> 4;       // k sub-block 0..3
    const int rsel = lane & 15;

    // XCD-aware bijective swizzle (nwg = 512, divisible by 8)
    const int bid = blockIdx.x;
    const int swz = (bid & 7) * 64 + (bid >> 3);
    const int tm  = swz & 127, tn = swz >> 7;
    const int m0  = tm * 256,  n0 = tn * 256;

    // staging source: chunk c=tid -> row c>>2, col8 = (c&3)^((c>>3)&3)
    // (pre-swizzled global source; LDS dest stays linear: lane*16B)
    const int crow = tid >> 2;
    const int ccol = ((tid & 3) ^ ((tid >> 3) & 3)) * 8;
    const ushortT* gA0 = A + (size_t)(m0 + crow) * K + ccol;
    const ushortT* gA1 = gA0 + (size_t)128 * K;   // chunks tid+512 = rows +128
    const ushortT* gB0 = W + (size_t)(n0 + crow) * K + ccol;
    const ushortT* gB1 = gB0 + (size_t)128 * K;

    // wave-uniform LDS dest bases (element offsets within a region)
    const int dst0 = wv * 512;          // chunks tid
    const int dst1 = 4096 + wv * 512;   // chunks tid+512

    // prologue: stage tiles 0,1,2 (12 loads), wait for tile 0 (<=8 outstanding)
    #pragma unroll
    for (int t = 0; t < 3; ++t) {
        ushortT* ra = lds + t * 16384;
        ushortT* rb = ra + 8192;
        gld16(gA0 + t * 32, ra + dst0);
        gld16(gA1 + t * 32, ra + dst1);
        gld16(gB0 + t * 32, rb + dst0);
        gld16(gB1 + t * 32, rb + dst1);
    }
    asm volatile("s_waitcnt vmcnt(8)" ::: "memory");
    __builtin_amdgcn_s_barrier();

    f32x4 acc[8][4] = {};
    const int NT = K >> 5;   // 32 K-tiles

    #pragma unroll 1
    for (int t = 0; t < NT; ++t) {
        const ushortT* ra = lds + (t & 3) * 16384;
        const ushortT* rb = ra + 8192;

        // ---------- phase A ----------
        short8 Bf[4], Af[4];
        #pragma unroll
        for (int fn = 0; fn < 4; ++fn) Bf[fn] = ldsfrag(rb, wn * 64 + fn * 16 + rsel, g);
        #pragma unroll
        for (int fm = 0; fm < 4; ++fm) Af[fm] = ldsfrag(ra, wm * 128 + fm * 16 + rsel, g);
        if (t + 3 < NT) {
            ushortT* wa = lds + ((t + 3) & 3) * 16384;
            gld16(gA0 + (t + 3) * 32, wa + dst0);
            gld16(gA1 + (t + 3) * 32, wa + dst1);
        }
        asm volatile("" ::: "memory");
        __builtin_amdgcn_s_barrier();
        asm volatile("s_waitcnt lgkmcnt(0)" ::: "memory");
        __builtin_amdgcn_sched_barrier(0);
        __builtin_amdgcn_s_setprio(1);
        #pragma unroll
        for (int fm = 0; fm < 4; ++fm)
            #pragma unroll
            for (int fn = 0; fn < 4; ++fn)
                acc[fm][fn] = __builtin_amdgcn_mfma_f32_16x16x32_bf16(Af[fm], Bf[fn], acc[fm][fn], 0, 0, 0);
        __builtin_amdgcn_s_setprio(0);
        asm volatile("" ::: "memory");
        __builtin_amdgcn_s_barrier();

        // ---------- phase B ----------
        #pragma unroll
        for (int fm = 0; fm < 4; ++fm) Af[fm] = ldsfrag(ra, wm * 128 + 64 + fm * 16 + rsel, g);
        if (t + 3 < NT) {
            ushortT* wb = lds + ((t + 3) & 3) * 16384 + 8192;
            gld16(gB0 + (t + 3) * 32, wb + dst0);
            gld16(gB1 + (t + 3) * 32, wb + dst1);
        }
        if (t < NT - 3)      { asm volatile("s_waitcnt vmcnt(8)" ::: "memory"); }
        else if (t == NT - 3){ asm volatile("s_waitcnt vmcnt(4)" ::: "memory"); }
        else if (t == NT - 2){ asm volatile("s_waitcnt vmcnt(0)" ::: "memory"); }
        asm volatile("" ::: "memory");
        __builtin_amdgcn_s_barrier();
        asm volatile("s_waitcnt lgkmcnt(0)" ::: "memory");
        __builtin_amdgcn_sched_barrier(0);
        __builtin_amdgcn_s_setprio(1);
        #pragma unroll
        for (int fm = 0; fm < 4; ++fm)
            #pragma unroll
            for (int fn = 0; fn < 4; ++fn)
                acc[4 + fm][fn] = __builtin_amdgcn_mfma_f32_16x16x32_bf16(Af[fm], Bf[fn], acc[4 + fm][fn], 0, 0, 0);
        __builtin_amdgcn_s_setprio(0);
        asm volatile("" ::: "memory");
        __builtin_amdgcn_s_barrier();
    }

    // epilogue: C/D layout col = rsel, row = g*4 + e (within 16x16 frag)
    // global row = m0 + wm*128 + am*16 + g*4 + e  (am = 0..7, uniform formula)
    #pragma unroll
    for (int fn = 0; fn < 4; ++fn) {
        const int colb = n0 + wn * 64 + fn * 16 + rsel;
        const int d    = colb & 63;
        const float bv = bias[colb];
        #pragma unroll
        for (int am = 0; am < 8; ++am) {
            const int rowbase = m0 + wm * 128 + am * 16 + g * 4;
            #pragma unroll
            for (int e = 0; e < 4; ++e) {
                const int row = rowbase + e;
                const float val = acc[am][fn][e] + bv;
                if (MODE == 1) {
                    // present: (B, H, T, 64) fp32, pre-rope
                    const int b = row >> 13, t = row & 8191;
                    const int h = colb >> 6;
                    Cf[(((size_t)b * 16 + h) * 8192 + t) * 64 + d] = val;
                }
                if (MODE == 2) {
                    Cf[(size_t)row * N + colb] = val;
                } else {
                    // rope: pair (d, d^1) sits at lane^1, same row
                    const float pv = __shfl_xor(val, 1, 64);
                    float ov = val;
                    if (d < 32) {
                        const int t = row & 8191;
                        const float2 cs = tab[t * 16 + (d >> 1)];
                        ov = (d & 1) ? fmaf(val, cs.x,  pv * cs.y)
                                     : fmaf(val, cs.x, -pv * cs.y);
                    }
                    Cb[(size_t)row * N + colb] = f2bf(ov);
                }
            }
        }
    }
}

// ---------------- neighborhood attention ----------------
// wave = 8 queries x 8 dim-chunks; lane = tloc*8 + c  (8 consecutive lanes
// cover one contiguous 128B row segment). q/k/v already roped.
__global__ __launch_bounds__(256) void natt_kernel(
    const ushortT* __restrict__ Q,
    const ushortT* __restrict__ Kl,
    const ushortT* __restrict__ Vl,
    ushortT*       __restrict__ O)
{
    const int T = 8192;
    const int tid  = threadIdx.x;
    const int lane = tid & 63;
    const int tloc = lane >> 3;
    const int c    = lane & 7;

    const int wq   = (blockIdx.x * 256 + tid) >> 6;  // wave-group id
    const int qidx = wq * 8 + tloc;
    const int t = qidx & (T - 1);
    const int h = (qidx >> 13) & 15;
    const int b = qidx >> 17;

    const int shifts[4] = {0, 2, 3, 4};
    const int sh = shifts[h >> 2];
    const int dd = 1 << sh;

    const int r  = t & (dd - 1);
    const int p  = t >> sh;
    const int Lr = ((T - 1 - r) >> sh) + 1;
    int s = p - 3;
    const int smax = Lr - 7;
    s = s < 0 ? 0 : (s > smax ? smax : s);
    const int tbase = r + (s << sh);

    const size_t qoff = ((size_t)(b * T + t)) * 1024 + h * 64 + c * 8;
    float qf[8];
    unpack8(*reinterpret_cast<const uint4*>(Q + qoff), qf);

    const size_t cbase = ((size_t)b * T) * 1024 + h * 64 + c * 8;

    float sc[7];
    #pragma unroll
    for (int j = 0; j < 7; ++j) {
        const int tj = tbase + (j << sh);
        float kf[8];
        unpack8(*reinterpret_cast<const uint4*>(Kl + cbase + (size_t)tj * 1024), kf);
        float pp = 0.f;
        #pragma unroll
        for (int i = 0; i < 8; ++i) pp = fmaf(qf[i], kf[i], pp);
        pp += __shfl_xor(pp, 1, 64);
        pp += __shfl_xor(pp, 2, 64);
        pp += __shfl_xor(pp, 4, 64);
        sc[j] = pp;
    }

    float mx = sc[0];
    #pragma unroll
    for (int j = 1; j < 7; ++j) mx = fmaxf(mx, sc[j]);
    float den = 0.f;
    #pragma unroll
    for (int j = 0; j < 7; ++j) { sc[j] = __expf(sc[j] - mx); den += sc[j]; }
    const float inv = 1.0f / den;

    float out[8] = {};
    #pragma unroll
    for (int j = 0; j < 7; ++j) {
        const int tj = tbase + (j << sh);
        float vf[8];
        unpack8(*reinterpret_cast<const uint4*>(Vl + cbase + (size_t)tj * 1024), vf);
        #pragma unroll
        for (int i = 0; i < 8; ++i) out[i] = fmaf(sc[j], vf[i], out[i]);
    }

    short8 ov;
    #pragma unroll
    for (int i = 0; i < 8; ++i) ov[i] = (short)f2bf(out[i] * inv);
    *reinterpret_cast<short8*>(const_cast<ushortT*>(O + qoff)) = ov;
}

// ---------------- launcher ----------------
extern "C" void kernel_launch(void* const* d_in, const int* in_sizes, int n_in,
                              void* d_out, int out_size, void* d_ws, size_t ws_size,
                              hipStream_t stream)
{
    const float* x  = (const float*)d_in[0];
    const float* wq = (const float*)d_in[1];
    const float* bq = (const float*)d_in[2];
    const float* wk = (const float*)d_in[3];
    const float* bk = (const float*)d_in[4];
    const float* wv = (const float*)d_in[5];
    const float* bv = (const float*)d_in[6];
    const float* wp = (const float*)d_in[7];
    const float* bp = (const float*)d_in[8];

    const int B = 4, T = 8192, C = 1024;
    const int M = B * T;                    // 32768
    const size_t MC = (size_t)M * C;        // 33,554,432

    char* ws = (char*)d_ws;
    ushortT* xb   = (ushortT*)ws;                                   // 64MB (reused as attn out)
    ushortT* wqb  = (ushortT*)(ws + (size_t)64 * 1024 * 1024);
    ushortT* wkb  = wqb + (size_t)C * C;
    ushortT* wvb  = wkb + (size_t)C * C;
    ushortT* wpb  = wvb + (size_t)C * C;
    ushortT* qlin = (ushortT*)(ws + (size_t)72 * 1024 * 1024);      // 64MB
    ushortT* klin = qlin + MC;                                      // 64MB
    ushortT* vlin = klin + MC;                                      // 64MB
    float2*  tab  = (float2*)(ws + (size_t)264 * 1024 * 1024);      // 1MB

    float* y     = (float*)d_out;
    float* presK = y + MC;
    float* presV = presK + MC;

    // allow 128 KB dynamic LDS on the GEMM instantiations (idempotent)
    hipFuncSetAttribute((const void*)gemm256_kernel<0>,
                        hipFuncAttributeMaxDynamicSharedMemorySize, 131072);
    hipFuncSetAttribute((const void*)gemm256_kernel<1>,
                        hipFuncAttributeMaxDynamicSharedMemorySize, 131072);
    hipFuncSetAttribute((const void*)gemm256_kernel<2>,
                        hipFuncAttributeMaxDynamicSharedMemorySize, 131072);

    rope_table_kernel<<<512, 256, 0, stream>>>(tab);

    f32_to_bf16_kernel<<<(int)(MC / 4 / 256), 256, 0, stream>>>(x, xb, (int)(MC / 4));
    const int wn4 = C * C / 4;
    f32_to_bf16_kernel<<<(wn4 + 255) / 256, 256, 0, stream>>>(wq, wqb, wn4);
    f32_to_bf16_kernel<<<(wn4 + 255) / 256, 256, 0, stream>>>(wk, wkb, wn4);
    f32_to_bf16_kernel<<<(wn4 + 255) / 256, 256, 0, stream>>>(wv, wvb, wn4);
    f32_to_bf16_kernel<<<(wn4 + 255) / 256, 256, 0, stream>>>(wp, wpb, wn4);

    const int nwg = (M / 256) * (C / 256);   // 128*4 = 512
    gemm256_kernel<0><<<nwg, 512, 131072, stream>>>(xb, wqb, bq, tab, qlin, nullptr, M, C, C);
    gemm256_kernel<1><<<nwg, 512, 131072, stream>>>(xb, wkb, bk, tab, klin, presK, M, C, C);
    gemm256_kernel<1><<<nwg, 512, 131072, stream>>>(xb, wvb, bv, tab, vlin, presV, M, C, C);

    natt_kernel<<<(B * 16 * T) / 32, 256, 0, stream>>>(qlin, klin, vlin, xb);

    gemm256_kernel<2><<<nwg, 512, 131072, stream>>>(xb, wpb, bp, tab, nullptr, y, M, C, C);
}